// Round 17
// baseline (111.976 us; speedup 1.0000x reference)
//
#include <hip/hip_runtime.h>
#include <hip/hip_bf16.h>

#define DD 32
#define M_ROWS 1000
#define EPS 1e-5f
#define LROW 68   // padded LDS row stride in floats

typedef float f32x16 __attribute__((ext_vector_type(16)));
typedef float f32x8  __attribute__((ext_vector_type(8)));
typedef float f32x4  __attribute__((ext_vector_type(4)));
typedef short bf16x8 __attribute__((ext_vector_type(8)));

// ws layout (floats):
//   g      @0      (32000)   g[m][k] = (f'_m .* hg) @ fw1   (natural order)
//   fphgp  @32000  (32000)   f'_m[d]*hg[d], C-layout permuted per row
//   Srow   @64000  (1024)
//   consts @65024  (64)   [0:32)=c, [32]=E, [33]=F
//   eperm  @65088  (32)   fg[d]*ow[d], C-layout permuted
//   cbperm @65120  (32)   hbt[d]+fb2[d], C-layout permuted
//   aextT  @65152  (512 floats = 1024 ushorts)  fw2^T bf16 [32 d][32 k]
//   fpb    @65664  (16000 floats = 32000 ushorts) f' rows bf16

static __device__ __forceinline__ bf16x8 cvt8(f32x8 v) {
    bf16x8 r;
#pragma unroll
    for (int e = 0; e < 8; ++e) {
        __hip_bfloat16 b = __float2bfloat16(v[e]);
        r[e] = __builtin_bit_cast(short, b);
    }
    return r;
}

static __device__ __forceinline__ float grp4_sum(float v) {
    v += __shfl_xor(v, 1);
    v += __shfl_xor(v, 2);
    return v;
}

// C-layout permutation: perm index for dim d
static __device__ __forceinline__ int cperm(int d) {
    return (d & 3) | (((d >> 3) & 3) << 2) | (((d >> 2) & 1) << 4);
}

// ---------- front: 16 rows/block, 4 lanes per row; lane owns 8 of 32 dims ----------
__global__ __launch_bounds__(64) void front_kernel(
    const float* __restrict__ feat,
    const float* __restrict__ aw1, const float* __restrict__ ab1,
    const float* __restrict__ aw2, const float* __restrict__ ab2,
    const float* __restrict__ ag,  const float* __restrict__ abt,
    const float* __restrict__ hg,
    const float* __restrict__ fw1, const float* __restrict__ fb1,
    const float* __restrict__ hbt, const float* __restrict__ fw2,
    const float* __restrict__ fb2, const float* __restrict__ fg,
    const float* __restrict__ fbt, const float* __restrict__ ow,
    const float* __restrict__ ob,
    float* __restrict__ g, float* __restrict__ fphgp, float* __restrict__ Srow,
    float* __restrict__ consts, float* __restrict__ eperm, float* __restrict__ cbperm,
    unsigned short* __restrict__ aextT, unsigned short* __restrict__ fpb)
{
    const int tx = threadIdx.x;
    if (blockIdx.x == 63) {
        // ---- prep ----
        if (tx < DD) {
            float c = fb1[tx];
#pragma unroll
            for (int d = 0; d < DD; ++d) c = fmaf(hbt[d], fw1[d*DD + tx], c);
            consts[tx] = c;
            const int r = tx & 15, hh = tx >> 4;
            const int d = (r & 3) + 8 * (r >> 2) + 4 * hh;
            eperm[tx]  = fg[d] * ow[d];
            cbperm[tx] = hbt[d] + fb2[d];
        }
        if (tx == 0) {
            float E = 0.f, F = ob[0];
#pragma unroll
            for (int d = 0; d < DD; ++d) { E += fg[d] * ow[d]; F = fmaf(fbt[d], ow[d], F); }
            consts[32] = E; consts[33] = F;
        }
        for (int idx = tx; idx < 32 * 32; idx += 64) {
            const int d = idx >> 5, k = idx & 31;
            __hip_bfloat16 b = __float2bfloat16(fw2[k * DD + d]);
            aextT[idx] = __builtin_bit_cast(unsigned short, b);
        }
        return;
    }
    const int m = blockIdx.x * 16 + (tx >> 2);
    const int q = tx & 3;
    if (m >= M_ROWS) return;
    const int b = tx & 60;          // group base lane (block = 1 wave)
    const int kb = q << 3;          // owned dim range [kb, kb+8)

    const f32x8 xo = *reinterpret_cast<const f32x8*>(feat + m * DD + kb);
    f32x8 X0, X1, X2, X3;
#pragma unroll
    for (int e = 0; e < 8; ++e) {
        X0[e] = __shfl(xo[e], b);     X1[e] = __shfl(xo[e], b + 1);
        X2[e] = __shfl(xo[e], b + 2); X3[e] = __shfl(xo[e], b + 3);
    }
    f32x8 h = *reinterpret_cast<const f32x8*>(ab1 + kb);
#pragma unroll
    for (int d = 0; d < DD; ++d) {
        const float xv = d < 8 ? X0[d] : d < 16 ? X1[d-8] : d < 24 ? X2[d-16] : X3[d-24];
        const f32x8 w = *reinterpret_cast<const f32x8*>(aw1 + d * DD + kb);
        h = h + xv * w;
    }
#pragma unroll
    for (int e = 0; e < 8; ++e) h[e] = fmaxf(h[e], 0.f);
    f32x8 H0, H1, H2, H3;
#pragma unroll
    for (int e = 0; e < 8; ++e) {
        H0[e] = __shfl(h[e], b);     H1[e] = __shfl(h[e], b + 1);
        H2[e] = __shfl(h[e], b + 2); H3[e] = __shfl(h[e], b + 3);
    }
    f32x8 y = xo + *reinterpret_cast<const f32x8*>(ab2 + kb);
#pragma unroll
    for (int k = 0; k < DD; ++k) {
        const float hv = k < 8 ? H0[k] : k < 16 ? H1[k-8] : k < 24 ? H2[k-16] : H3[k-24];
        const f32x8 w = *reinterpret_cast<const f32x8*>(aw2 + k * DD + kb);
        y = y + hv * w;
    }
    float sm = 0.f;
#pragma unroll
    for (int e = 0; e < 8; ++e) sm += y[e];
    const float mean = grp4_sum(sm) * (1.0f / DD);
    float vr = 0.f;
#pragma unroll
    for (int e = 0; e < 8; ++e) { const float tv = y[e] - mean; vr = fmaf(tv, tv, vr); }
    const float s = rsqrtf(grp4_sum(vr) * (1.0f / DD) + EPS);
    const f32x8 agv  = *reinterpret_cast<const f32x8*>(ag + kb);
    const f32x8 abtv = *reinterpret_cast<const f32x8*>(abt + kb);
    f32x8 f;
#pragma unroll
    for (int e = 0; e < 8; ++e) f[e] = (y[e] - mean) * s * agv[e] + abtv[e];
    float fs = 0.f;
#pragma unroll
    for (int e = 0; e < 8; ++e) fs += f[e];
    const float fm = grp4_sum(fs) * (1.0f / DD);
    const f32x8 fp = f - fm;
    float Sl = 0.f;
#pragma unroll
    for (int e = 0; e < 8; ++e) Sl = fmaf(fp[e], fp[e], Sl);
    const float S = grp4_sum(Sl);
    if (q == 0) Srow[m] = S;
    const f32x8 hgv = *reinterpret_cast<const f32x8*>(hg + kb);
    const f32x8 fph = fp * hgv;
    // C-layout permuted scatter of fphg
#pragma unroll
    for (int e = 0; e < 8; ++e)
        fphgp[m * DD + cperm(kb + e)] = fph[e];
    *reinterpret_cast<bf16x8*>(fpb + m * DD + kb) = cvt8(fp);
    // g row = fph_full @ fw1, lane's 8 outputs (natural order)
    f32x8 P0, P1, P2, P3;
#pragma unroll
    for (int e = 0; e < 8; ++e) {
        P0[e] = __shfl(fph[e], b);     P1[e] = __shfl(fph[e], b + 1);
        P2[e] = __shfl(fph[e], b + 2); P3[e] = __shfl(fph[e], b + 3);
    }
    f32x8 gr = {0.f,0.f,0.f,0.f,0.f,0.f,0.f,0.f};
#pragma unroll
    for (int d = 0; d < DD; ++d) {
        const float pv = d < 8 ? P0[d] : d < 16 ? P1[d-8] : d < 24 ? P2[d-16] : P3[d-24];
        const f32x8 w = *reinterpret_cast<const f32x8*>(fw1 + d * DD + kb);
        gr = gr + pv * w;
    }
    *reinterpret_cast<f32x8*>(g + m * DD + kb) = gr;
}

// ---------- pair head: symmetric, triangular flat grid (544 live blocks) ----------
// block = 16 i x 64 j; wave = 4 i x 64 j (8 tiles). Q in-wave via MFMA.
// C layout: col=l5=pair, row d=(r&3)+8*(r>>2)+4*h2
__global__ __launch_bounds__(256, 4) void pair_head_kernel(
    const float* __restrict__ g,      const float* __restrict__ fphgp,
    const float* __restrict__ Srow,   const float* __restrict__ ddg,
    const float* __restrict__ consts, const float* __restrict__ eperm,
    const float* __restrict__ cbperm, const unsigned short* __restrict__ aextT,
    const unsigned short* __restrict__ fpb,
    float* __restrict__ out)
{
    __shared__ float lds[64 * LROW];   // 17408 B
    __shared__ float lds2[64 * 17];    // 4352 B  res[j_local][i_local], stride 17

    const int tx   = threadIdx.x;
    const int wid  = tx >> 6;
    const int lane = tx & 63;
    const int l5   = lane & 31;
    const int h2   = lane >> 5;

    // triangular decode: block b -> (jg, iy); cum(jg) = 2jg^2+2jg; live rows 4jg+4
    const int bid = blockIdx.x;
    int jg = (int)((-1.0f + sqrtf(1.0f + 2.0f * (float)bid)) * 0.5f);
    while (2 * (jg + 1) * (jg + 1) + 2 * (jg + 1) <= bid) ++jg;
    while (2 * jg * jg + 2 * jg > bid) --jg;
    const int iy  = bid - (2 * jg * jg + 2 * jg);
    const int ib0 = iy * 16;                      // block's first i
    const int ib  = ib0 + wid * 4;                // wave's first i

    // ---- stage j-panel: 64 rows x (g 32f | fphgp 32f), one f32x16 per thread ----
    {
        const int r    = tx >> 2;          // row 0..63
        const int part = tx & 3;
        const int srcr = min(jg * 64 + r, M_ROWS - 1);
        const float* src = ((part >> 1) ? fphgp : g) + srcr * DD + (part & 1) * 16;
        float* dst = lds + r * LROW + (part >> 1) * 32 + (part & 1) * 16;
        *reinterpret_cast<f32x16*>(dst) = *reinterpret_cast<const f32x16*>(src);
    }

    // ---- Q via MFMA (overlaps the LDS stage; no LDS dependency) ----
    const int j0  = jg * 64 + l5;
    const int j1  = jg * 64 + 32 + l5;
    const int jc0 = j0 < M_ROWS ? j0 : M_ROWS - 1;
    const int jc1 = j1 < M_ROWS ? j1 : M_ROWS - 1;

    const int ia = min(ib + l5, M_ROWS - 1);   // A rows (only l5<4 read from C)
    const bf16x8 aq0 = *reinterpret_cast<const bf16x8*>(fpb + ia * DD + h2 * 8);
    const bf16x8 aq1 = *reinterpret_cast<const bf16x8*>(fpb + ia * DD + 16 + h2 * 8);

    float qv[8];
#pragma unroll
    for (int t = 0; t < 2; ++t) {
        const int jc = t ? jc1 : jc0;
        const bf16x8 bq0 = *reinterpret_cast<const bf16x8*>(fpb + jc * DD + h2 * 8);
        const bf16x8 bq1 = *reinterpret_cast<const bf16x8*>(fpb + jc * DD + 16 + h2 * 8);
        f32x16 qa;
#pragma unroll
        for (int r = 0; r < 16; ++r) qa[r] = 0.f;
        qa = __builtin_amdgcn_mfma_f32_32x32x16_bf16(aq0, bq0, qa, 0, 0, 0);
        qa = __builtin_amdgcn_mfma_f32_32x32x16_bf16(aq1, bq1, qa, 0, 0, 0);
#pragma unroll
        for (int ii = 0; ii < 4; ++ii) {
            const float other = __shfl_xor(qa[ii], 32);
            qv[2 * ii + t] = h2 ? other : qa[ii];
        }
    }

    const bf16x8 af0 = *reinterpret_cast<const bf16x8*>(aextT + l5 * 32 + h2 * 8);
    const bf16x8 af1 = *reinterpret_cast<const bf16x8*>(aextT + l5 * 32 + 16 + h2 * 8);

    const f32x8  ckA = *reinterpret_cast<const f32x8*>(consts + h2 * 8);
    const f32x8  ckB = *reinterpret_cast<const f32x8*>(consts + 16 + h2 * 8);
    const f32x16 cbp = *reinterpret_cast<const f32x16*>(cbperm + h2 * 16);
    const f32x16 ep  = *reinterpret_cast<const f32x16*>(eperm  + h2 * 16);
    const float E = consts[32];
    const float Fc = consts[33];

    const float Sj0 = Srow[jc0], Sj1 = Srow[jc1];
    const float dj0 = ddg[jc0],  dj1 = ddg[jc1];

    __syncthreads();

#pragma unroll 2
    for (int ii = 0; ii < 4; ++ii) {
        const int i  = ib + ii;
        const int ic = min(i, M_ROWS - 1);
        // i-side: wave-uniform addresses -> scalar loads
        const f32x8  gikA   = *reinterpret_cast<const f32x8*>(g + ic * DD + h2 * 8);
        const f32x8  gikB   = *reinterpret_cast<const f32x8*>(g + ic * DD + 16 + h2 * 8);
        const f32x16 fiperm = *reinterpret_cast<const f32x16*>(fphgp + ic * DD + h2 * 16);
        const float Si = Srow[ic];
        const float Fd = Fc + ddg[ic];

#pragma unroll
        for (int t = 0; t < 2; ++t) {
            const float* base = lds + (t * 32 + l5) * LROW;
            const f32x8  gjA = *reinterpret_cast<const f32x8*>(base + h2 * 8);
            const f32x8  gjB = *reinterpret_cast<const f32x8*>(base + 16 + h2 * 8);
            const f32x16 fjp = *reinterpret_cast<const f32x16*>(base + 32 + h2 * 16);
            const float Sj = t ? Sj1 : Sj0;
            const float dj = t ? dj1 : dj0;
            const float qd = qv[2 * ii + t];

            const float s = rsqrtf(fmaf(Si + Sj + 2.f * qd, 1.0f / DD, EPS));

            f32x8 tA = (gikA + gjA) * s + ckA;
            f32x8 tB = (gikB + gjB) * s + ckB;
#pragma unroll
            for (int e = 0; e < 8; ++e) { tA[e] = fmaxf(tA[e], 0.f); tB[e] = fmaxf(tB[e], 0.f); }
            const bf16x8 B0 = cvt8(tA);
            const bf16x8 B1 = cvt8(tB);

            f32x16 acc = cbp;
            acc = __builtin_amdgcn_mfma_f32_32x32x16_bf16(af0, B0, acc, 0, 0, 0);
            acc = __builtin_amdgcn_mfma_f32_32x32x16_bf16(af1, B1, acc, 0, 0, 0);

            float sy = 0.f, syy = 0.f, sye = 0.f;
#pragma unroll
            for (int r = 0; r < 16; ++r) {
                const float yv = fmaf(s, fiperm[r] + fjp[r], acc[r]);
                sy += yv; syy = fmaf(yv, yv, syy); sye = fmaf(yv, ep[r], sye);
            }
            sy  += __shfl_xor(sy, 32);
            syy += __shfl_xor(syy, 32);
            sye += __shfl_xor(sye, 32);
            const float m2   = sy * (1.0f / DD);
            const float var2 = fmaf(-m2, m2, syy * (1.0f / DD));
            const float s2   = rsqrtf(var2 + EPS);
            const float res  = fmaf(s2, fmaf(-m2, E, sye), Fd) + dj;
            const int j = jg * 64 + t * 32 + l5;
            if (h2 == 0) {
                lds2[(t * 32 + l5) * 17 + (wid * 4 + ii)] = res;
                if (j < M_ROWS && i < M_ROWS && i <= j) out[i * M_ROWS + j] = res;
            }
        }
    }

    __syncthreads();

    // ---- mirror: out[j][i] = res(i,j) for j > i, coalesced 16-lane segments ----
#pragma unroll
    for (int p = 0; p < 4; ++p) {
        const int jl = (tx >> 4) + p * 16;
        const int il = tx & 15;
        const int jgl = jg * 64 + jl;
        const int igl = ib0 + il;
        if (jgl > igl && jgl < M_ROWS && igl < M_ROWS)
            out[jgl * M_ROWS + igl] = lds2[jl * 17 + il];
    }
}

extern "C" void kernel_launch(void* const* d_in, const int* in_sizes, int n_in,
                              void* d_out, int out_size, void* d_ws, size_t ws_size,
                              hipStream_t stream) {
    const float* feat = (const float*)d_in[0];
    const float* ddg  = (const float*)d_in[1];
    const float* aw1  = (const float*)d_in[2];
    const float* ab1  = (const float*)d_in[3];
    const float* aw2  = (const float*)d_in[4];
    const float* ab2  = (const float*)d_in[5];
    const float* ag   = (const float*)d_in[6];
    const float* abt  = (const float*)d_in[7];
    const float* hg   = (const float*)d_in[8];
    const float* hbt  = (const float*)d_in[9];
    const float* fw1  = (const float*)d_in[10];
    const float* fb1  = (const float*)d_in[11];
    const float* fw2  = (const float*)d_in[12];
    const float* fb2  = (const float*)d_in[13];
    const float* fg   = (const float*)d_in[14];
    const float* fbt  = (const float*)d_in[15];
    const float* ow   = (const float*)d_in[16];
    const float* ob   = (const float*)d_in[17];
    float* out = (float*)d_out;

    float* ws      = (float*)d_ws;
    float* g       = ws;             // 32000
    float* fphgp   = ws + 32000;     // 32000
    float* Srow    = ws + 64000;     // 1024
    float* consts  = ws + 65024;     // 64
    float* eperm   = ws + 65088;     // 32
    float* cbperm  = ws + 65120;     // 32
    unsigned short* aextT = (unsigned short*)(ws + 65152);  // 1024 ushorts
    unsigned short* fpb   = (unsigned short*)(ws + 65664);  // 32000 ushorts

    front_kernel<<<dim3(64), dim3(64), 0, stream>>>(
        feat, aw1, ab1, aw2, ab2, ag, abt, hg,
        fw1, fb1, hbt, fw2, fb2, fg, fbt, ow, ob,
        g, fphgp, Srow, consts, eperm, cbperm, aextT, fpb);
    pair_head_kernel<<<dim3(544), dim3(256), 0, stream>>>(
        g, fphgp, Srow, ddg, consts, eperm, cbperm, aextT, fpb, out);
}

// Round 18
// 22.869 us; speedup vs baseline: 4.8965x; 4.8965x over previous
//
#include <hip/hip_runtime.h>
#include <hip/hip_bf16.h>

#define DD 32
#define M_ROWS 1000
#define EPS 1e-5f
#define LROW 68   // padded LDS row stride in floats

typedef float f32x16 __attribute__((ext_vector_type(16)));
typedef float f32x8  __attribute__((ext_vector_type(8)));
typedef float f32x4  __attribute__((ext_vector_type(4)));
typedef short bf16x8 __attribute__((ext_vector_type(8)));

// ws layout (floats):
//   g      @0      (32000)   g[m][k] = (f'_m .* hg) @ fw1   (natural order)
//   fphgp  @32000  (32000)   f'_m[d]*hg[d], C-layout permuted per row
//   Srow   @64000  (1024)
//   consts @65024  (64)   [0:32)=c, [32]=E, [33]=F
//   eperm  @65088  (32)   fg[d]*ow[d], C-layout permuted
//   cbperm @65120  (32)   hbt[d]+fb2[d], C-layout permuted
//   aextT  @65152  (512 floats = 1024 ushorts)  fw2^T bf16 [32 d][32 k]
//   fpb    @65664  (16000 floats = 32000 ushorts) f' rows bf16

static __device__ __forceinline__ bf16x8 cvt8(f32x8 v) {
    bf16x8 r;
#pragma unroll
    for (int e = 0; e < 8; ++e) {
        __hip_bfloat16 b = __float2bfloat16(v[e]);
        r[e] = __builtin_bit_cast(short, b);
    }
    return r;
}

static __device__ __forceinline__ float grp4_sum(float v) {
    v += __shfl_xor(v, 1);
    v += __shfl_xor(v, 2);
    return v;
}

// C-layout permutation: perm index for dim d
static __device__ __forceinline__ int cperm(int d) {
    return (d & 3) | (((d >> 3) & 3) << 2) | (((d >> 2) & 1) << 4);
}

// ---------- front: 16 rows/block, 4 lanes per row; lane owns 8 of 32 dims ----------
__global__ __launch_bounds__(64) void front_kernel(
    const float* __restrict__ feat,
    const float* __restrict__ aw1, const float* __restrict__ ab1,
    const float* __restrict__ aw2, const float* __restrict__ ab2,
    const float* __restrict__ ag,  const float* __restrict__ abt,
    const float* __restrict__ hg,
    const float* __restrict__ fw1, const float* __restrict__ fb1,
    const float* __restrict__ hbt, const float* __restrict__ fw2,
    const float* __restrict__ fb2, const float* __restrict__ fg,
    const float* __restrict__ fbt, const float* __restrict__ ow,
    const float* __restrict__ ob,
    float* __restrict__ g, float* __restrict__ fphgp, float* __restrict__ Srow,
    float* __restrict__ consts, float* __restrict__ eperm, float* __restrict__ cbperm,
    unsigned short* __restrict__ aextT, unsigned short* __restrict__ fpb)
{
    const int tx = threadIdx.x;
    if (blockIdx.x == 63) {
        // ---- prep ----
        if (tx < DD) {
            float c = fb1[tx];
#pragma unroll
            for (int d = 0; d < DD; ++d) c = fmaf(hbt[d], fw1[d*DD + tx], c);
            consts[tx] = c;
            const int r = tx & 15, hh = tx >> 4;
            const int d = (r & 3) + 8 * (r >> 2) + 4 * hh;
            eperm[tx]  = fg[d] * ow[d];
            cbperm[tx] = hbt[d] + fb2[d];
        }
        if (tx == 0) {
            float E = 0.f, F = ob[0];
#pragma unroll
            for (int d = 0; d < DD; ++d) { E += fg[d] * ow[d]; F = fmaf(fbt[d], ow[d], F); }
            consts[32] = E; consts[33] = F;
        }
        for (int idx = tx; idx < 32 * 32; idx += 64) {
            const int d = idx >> 5, k = idx & 31;
            __hip_bfloat16 b = __float2bfloat16(fw2[k * DD + d]);
            aextT[idx] = __builtin_bit_cast(unsigned short, b);
        }
        return;
    }
    const int m = blockIdx.x * 16 + (tx >> 2);
    const int q = tx & 3;
    if (m >= M_ROWS) return;
    const int b = tx & 60;          // group base lane (block = 1 wave)
    const int kb = q << 3;          // owned dim range [kb, kb+8)

    const f32x8 xo = *reinterpret_cast<const f32x8*>(feat + m * DD + kb);
    f32x8 X0, X1, X2, X3;
#pragma unroll
    for (int e = 0; e < 8; ++e) {
        X0[e] = __shfl(xo[e], b);     X1[e] = __shfl(xo[e], b + 1);
        X2[e] = __shfl(xo[e], b + 2); X3[e] = __shfl(xo[e], b + 3);
    }
    f32x8 h = *reinterpret_cast<const f32x8*>(ab1 + kb);
#pragma unroll
    for (int d = 0; d < DD; ++d) {
        const float xv = d < 8 ? X0[d] : d < 16 ? X1[d-8] : d < 24 ? X2[d-16] : X3[d-24];
        const f32x8 w = *reinterpret_cast<const f32x8*>(aw1 + d * DD + kb);
        h = h + xv * w;
    }
#pragma unroll
    for (int e = 0; e < 8; ++e) h[e] = fmaxf(h[e], 0.f);
    f32x8 H0, H1, H2, H3;
#pragma unroll
    for (int e = 0; e < 8; ++e) {
        H0[e] = __shfl(h[e], b);     H1[e] = __shfl(h[e], b + 1);
        H2[e] = __shfl(h[e], b + 2); H3[e] = __shfl(h[e], b + 3);
    }
    f32x8 y = xo + *reinterpret_cast<const f32x8*>(ab2 + kb);
#pragma unroll
    for (int k = 0; k < DD; ++k) {
        const float hv = k < 8 ? H0[k] : k < 16 ? H1[k-8] : k < 24 ? H2[k-16] : H3[k-24];
        const f32x8 w = *reinterpret_cast<const f32x8*>(aw2 + k * DD + kb);
        y = y + hv * w;
    }
    float sm = 0.f;
#pragma unroll
    for (int e = 0; e < 8; ++e) sm += y[e];
    const float mean = grp4_sum(sm) * (1.0f / DD);
    float vr = 0.f;
#pragma unroll
    for (int e = 0; e < 8; ++e) { const float tv = y[e] - mean; vr = fmaf(tv, tv, vr); }
    const float s = rsqrtf(grp4_sum(vr) * (1.0f / DD) + EPS);
    const f32x8 agv  = *reinterpret_cast<const f32x8*>(ag + kb);
    const f32x8 abtv = *reinterpret_cast<const f32x8*>(abt + kb);
    f32x8 f;
#pragma unroll
    for (int e = 0; e < 8; ++e) f[e] = (y[e] - mean) * s * agv[e] + abtv[e];
    float fs = 0.f;
#pragma unroll
    for (int e = 0; e < 8; ++e) fs += f[e];
    const float fm = grp4_sum(fs) * (1.0f / DD);
    const f32x8 fp = f - fm;
    float Sl = 0.f;
#pragma unroll
    for (int e = 0; e < 8; ++e) Sl = fmaf(fp[e], fp[e], Sl);
    const float S = grp4_sum(Sl);
    if (q == 0) Srow[m] = S;
    const f32x8 hgv = *reinterpret_cast<const f32x8*>(hg + kb);
    const f32x8 fph = fp * hgv;
    // C-layout permuted scatter of fphg
#pragma unroll
    for (int e = 0; e < 8; ++e)
        fphgp[m * DD + cperm(kb + e)] = fph[e];
    *reinterpret_cast<bf16x8*>(fpb + m * DD + kb) = cvt8(fp);
    // g row = fph_full @ fw1, lane's 8 outputs (natural order)
    f32x8 P0, P1, P2, P3;
#pragma unroll
    for (int e = 0; e < 8; ++e) {
        P0[e] = __shfl(fph[e], b);     P1[e] = __shfl(fph[e], b + 1);
        P2[e] = __shfl(fph[e], b + 2); P3[e] = __shfl(fph[e], b + 3);
    }
    f32x8 gr = {0.f,0.f,0.f,0.f,0.f,0.f,0.f,0.f};
#pragma unroll
    for (int d = 0; d < DD; ++d) {
        const float pv = d < 8 ? P0[d] : d < 16 ? P1[d-8] : d < 24 ? P2[d-16] : P3[d-24];
        const f32x8 w = *reinterpret_cast<const f32x8*>(fw1 + d * DD + kb);
        gr = gr + pv * w;
    }
    *reinterpret_cast<f32x8*>(g + m * DD + kb) = gr;
}

// ---------- pair head: symmetric, triangular flat grid (544 live blocks) ----------
// block = 16 i x 64 j; wave = 4 i x 64 j (8 tiles). Q in-wave via MFMA.
// C layout: col=l5=pair, row d=(r&3)+8*(r>>2)+4*h2
__global__ __launch_bounds__(256, 3) void pair_head_kernel(
    const float* __restrict__ g,      const float* __restrict__ fphgp,
    const float* __restrict__ Srow,   const float* __restrict__ ddg,
    const float* __restrict__ consts, const float* __restrict__ eperm,
    const float* __restrict__ cbperm, const unsigned short* __restrict__ aextT,
    const unsigned short* __restrict__ fpb,
    float* __restrict__ out)
{
    __shared__ float lds[64 * LROW];   // 17408 B
    __shared__ float lds2[64 * 17];    // 4352 B  res[j_local][i_local], stride 17

    const int tx   = threadIdx.x;
    const int wid  = tx >> 6;
    const int lane = tx & 63;
    const int l5   = lane & 31;
    const int h2   = lane >> 5;

    // triangular decode: block b -> (jg, iy); cum(jg) = 2jg^2+2jg; live rows 4jg+4
    const int bid = blockIdx.x;
    int jg = (int)((-1.0f + sqrtf(1.0f + 2.0f * (float)bid)) * 0.5f);
    while (2 * (jg + 1) * (jg + 1) + 2 * (jg + 1) <= bid) ++jg;
    while (2 * jg * jg + 2 * jg > bid) --jg;
    const int iy  = bid - (2 * jg * jg + 2 * jg);
    const int ib0 = iy * 16;                      // block's first i
    const int ib  = ib0 + wid * 4;                // wave's first i

    // ---- stage j-panel: 64 rows x (g 32f | fphgp 32f), one f32x16 per thread ----
    {
        const int r    = tx >> 2;          // row 0..63
        const int part = tx & 3;
        const int srcr = min(jg * 64 + r, M_ROWS - 1);
        const float* src = ((part >> 1) ? fphgp : g) + srcr * DD + (part & 1) * 16;
        float* dst = lds + r * LROW + (part >> 1) * 32 + (part & 1) * 16;
        *reinterpret_cast<f32x16*>(dst) = *reinterpret_cast<const f32x16*>(src);
    }

    // ---- Q via MFMA (overlaps the LDS stage; no LDS dependency) ----
    const int j0  = jg * 64 + l5;
    const int j1  = jg * 64 + 32 + l5;
    const int jc0 = j0 < M_ROWS ? j0 : M_ROWS - 1;
    const int jc1 = j1 < M_ROWS ? j1 : M_ROWS - 1;

    const int ia = min(ib + l5, M_ROWS - 1);   // A rows (only l5<4 read from C)
    const bf16x8 aq0 = *reinterpret_cast<const bf16x8*>(fpb + ia * DD + h2 * 8);
    const bf16x8 aq1 = *reinterpret_cast<const bf16x8*>(fpb + ia * DD + 16 + h2 * 8);

    float qv[8];
#pragma unroll
    for (int t = 0; t < 2; ++t) {
        const int jc = t ? jc1 : jc0;
        const bf16x8 bq0 = *reinterpret_cast<const bf16x8*>(fpb + jc * DD + h2 * 8);
        const bf16x8 bq1 = *reinterpret_cast<const bf16x8*>(fpb + jc * DD + 16 + h2 * 8);
        f32x16 qa;
#pragma unroll
        for (int r = 0; r < 16; ++r) qa[r] = 0.f;
        qa = __builtin_amdgcn_mfma_f32_32x32x16_bf16(aq0, bq0, qa, 0, 0, 0);
        qa = __builtin_amdgcn_mfma_f32_32x32x16_bf16(aq1, bq1, qa, 0, 0, 0);
#pragma unroll
        for (int ii = 0; ii < 4; ++ii) {
            const float other = __shfl_xor(qa[ii], 32);
            qv[2 * ii + t] = h2 ? other : qa[ii];
        }
    }

    const bf16x8 af0 = *reinterpret_cast<const bf16x8*>(aextT + l5 * 32 + h2 * 8);
    const bf16x8 af1 = *reinterpret_cast<const bf16x8*>(aextT + l5 * 32 + 16 + h2 * 8);

    const f32x8  ckA = *reinterpret_cast<const f32x8*>(consts + h2 * 8);
    const f32x8  ckB = *reinterpret_cast<const f32x8*>(consts + 16 + h2 * 8);
    const f32x16 cbp = *reinterpret_cast<const f32x16*>(cbperm + h2 * 16);
    const f32x16 ep  = *reinterpret_cast<const f32x16*>(eperm  + h2 * 16);
    const float E = consts[32];
    const float Fc = consts[33];

    const float Sj0 = Srow[jc0], Sj1 = Srow[jc1];
    const float dj0 = ddg[jc0],  dj1 = ddg[jc1];

    __syncthreads();

#pragma unroll
    for (int ii = 0; ii < 4; ++ii) {
        const int i  = ib + ii;
        const int ic = min(i, M_ROWS - 1);
        // i-side: wave-uniform addresses -> scalar loads
        const f32x8  gikA   = *reinterpret_cast<const f32x8*>(g + ic * DD + h2 * 8);
        const f32x8  gikB   = *reinterpret_cast<const f32x8*>(g + ic * DD + 16 + h2 * 8);
        const f32x16 fiperm = *reinterpret_cast<const f32x16*>(fphgp + ic * DD + h2 * 16);
        const float Si = Srow[ic];
        const float Fd = Fc + ddg[ic];

#pragma unroll
        for (int t = 0; t < 2; ++t) {
            const float* base = lds + (t * 32 + l5) * LROW;
            const f32x8  gjA = *reinterpret_cast<const f32x8*>(base + h2 * 8);
            const f32x8  gjB = *reinterpret_cast<const f32x8*>(base + 16 + h2 * 8);
            const f32x16 fjp = *reinterpret_cast<const f32x16*>(base + 32 + h2 * 16);
            const float Sj = t ? Sj1 : Sj0;
            const float dj = t ? dj1 : dj0;
            const float qd = qv[2 * ii + t];

            const float s = rsqrtf(fmaf(Si + Sj + 2.f * qd, 1.0f / DD, EPS));

            f32x8 tA = (gikA + gjA) * s + ckA;
            f32x8 tB = (gikB + gjB) * s + ckB;
#pragma unroll
            for (int e = 0; e < 8; ++e) { tA[e] = fmaxf(tA[e], 0.f); tB[e] = fmaxf(tB[e], 0.f); }
            const bf16x8 B0 = cvt8(tA);
            const bf16x8 B1 = cvt8(tB);

            f32x16 acc = cbp;
            acc = __builtin_amdgcn_mfma_f32_32x32x16_bf16(af0, B0, acc, 0, 0, 0);
            acc = __builtin_amdgcn_mfma_f32_32x32x16_bf16(af1, B1, acc, 0, 0, 0);

            float sy = 0.f, syy = 0.f, sye = 0.f;
#pragma unroll
            for (int r = 0; r < 16; ++r) {
                const float yv = fmaf(s, fiperm[r] + fjp[r], acc[r]);
                sy += yv; syy = fmaf(yv, yv, syy); sye = fmaf(yv, ep[r], sye);
            }
            sy  += __shfl_xor(sy, 32);
            syy += __shfl_xor(syy, 32);
            sye += __shfl_xor(sye, 32);
            const float m2   = sy * (1.0f / DD);
            const float var2 = fmaf(-m2, m2, syy * (1.0f / DD));
            const float s2   = rsqrtf(var2 + EPS);
            const float res  = fmaf(s2, fmaf(-m2, E, sye), Fd) + dj;
            const int j = jg * 64 + t * 32 + l5;
            if (h2 == 0) {
                lds2[(t * 32 + l5) * 17 + (wid * 4 + ii)] = res;
                if (j < M_ROWS && i < M_ROWS && i <= j) out[i * M_ROWS + j] = res;
            }
        }
    }

    __syncthreads();

    // ---- mirror: out[j][i] = res(i,j) for j > i, coalesced 16-lane segments ----
#pragma unroll
    for (int p = 0; p < 4; ++p) {
        const int jl = (tx >> 4) + p * 16;
        const int il = tx & 15;
        const int jgl = jg * 64 + jl;
        const int igl = ib0 + il;
        if (jgl > igl && jgl < M_ROWS && igl < M_ROWS)
            out[jgl * M_ROWS + igl] = lds2[jl * 17 + il];
    }
}

extern "C" void kernel_launch(void* const* d_in, const int* in_sizes, int n_in,
                              void* d_out, int out_size, void* d_ws, size_t ws_size,
                              hipStream_t stream) {
    const float* feat = (const float*)d_in[0];
    const float* ddg  = (const float*)d_in[1];
    const float* aw1  = (const float*)d_in[2];
    const float* ab1  = (const float*)d_in[3];
    const float* aw2  = (const float*)d_in[4];
    const float* ab2  = (const float*)d_in[5];
    const float* ag   = (const float*)d_in[6];
    const float* abt  = (const float*)d_in[7];
    const float* hg   = (const float*)d_in[8];
    const float* hbt  = (const float*)d_in[9];
    const float* fw1  = (const float*)d_in[10];
    const float* fb1  = (const float*)d_in[11];
    const float* fw2  = (const float*)d_in[12];
    const float* fb2  = (const float*)d_in[13];
    const float* fg   = (const float*)d_in[14];
    const float* fbt  = (const float*)d_in[15];
    const float* ow   = (const float*)d_in[16];
    const float* ob   = (const float*)d_in[17];
    float* out = (float*)d_out;

    float* ws      = (float*)d_ws;
    float* g       = ws;             // 32000
    float* fphgp   = ws + 32000;     // 32000
    float* Srow    = ws + 64000;     // 1024
    float* consts  = ws + 65024;     // 64
    float* eperm   = ws + 65088;     // 32
    float* cbperm  = ws + 65120;     // 32
    unsigned short* aextT = (unsigned short*)(ws + 65152);  // 1024 ushorts
    unsigned short* fpb   = (unsigned short*)(ws + 65664);  // 32000 ushorts

    front_kernel<<<dim3(64), dim3(64), 0, stream>>>(
        feat, aw1, ab1, aw2, ab2, ag, abt, hg,
        fw1, fb1, hbt, fw2, fb2, fg, fbt, ow, ob,
        g, fphgp, Srow, consts, eperm, cbperm, aextT, fpb);
    pair_head_kernel<<<dim3(544), dim3(256), 0, stream>>>(
        g, fphgp, Srow, ddg, consts, eperm, cbperm, aextT, fpb, out);
}

// Round 20
// 22.842 us; speedup vs baseline: 4.9021x; 1.0012x over previous
//
#include <hip/hip_runtime.h>
#include <hip/hip_bf16.h>

#define DD 32
#define M_ROWS 1000
#define EPS 1e-5f
#define LROW 68   // padded LDS row stride in floats

typedef float f32x16 __attribute__((ext_vector_type(16)));
typedef float f32x8  __attribute__((ext_vector_type(8)));
typedef float f32x4  __attribute__((ext_vector_type(4)));
typedef short bf16x8 __attribute__((ext_vector_type(8)));

// ws layout (floats):
//   g      @0      (32000)   g[m][k] = (f'_m .* hg) @ fw1   (natural order)
//   fphgp  @32000  (32000)   f'_m[d]*hg[d], C-layout permuted per row
//   Srow   @64000  (1024)
//   consts @65024  (64)   [0:32)=c, [32]=E, [33]=F
//   eperm  @65088  (32)   fg[d]*ow[d], C-layout permuted
//   cbperm @65120  (32)   hbt[d]+fb2[d], C-layout permuted
//   aextT  @65152  (512 floats = 1024 ushorts)  fw2^T bf16 [32 d][32 k]
//   fpb    @65664  (16000 floats = 32000 ushorts) f' rows bf16

static __device__ __forceinline__ bf16x8 cvt8(f32x8 v) {
    bf16x8 r;
#pragma unroll
    for (int e = 0; e < 8; ++e) {
        __hip_bfloat16 b = __float2bfloat16(v[e]);
        r[e] = __builtin_bit_cast(short, b);
    }
    return r;
}

static __device__ __forceinline__ float grp4_sum(float v) {
    v += __shfl_xor(v, 1);
    v += __shfl_xor(v, 2);
    return v;
}

// C-layout permutation: perm index for dim d
static __device__ __forceinline__ int cperm(int d) {
    return (d & 3) | (((d >> 3) & 3) << 2) | (((d >> 2) & 1) << 4);
}

// ---------- front: 16 rows/block, 4 lanes per row; lane owns 8 of 32 dims ----------
__global__ __launch_bounds__(64) void front_kernel(
    const float* __restrict__ feat,
    const float* __restrict__ aw1, const float* __restrict__ ab1,
    const float* __restrict__ aw2, const float* __restrict__ ab2,
    const float* __restrict__ ag,  const float* __restrict__ abt,
    const float* __restrict__ hg,
    const float* __restrict__ fw1, const float* __restrict__ fb1,
    const float* __restrict__ hbt, const float* __restrict__ fw2,
    const float* __restrict__ fb2, const float* __restrict__ fg,
    const float* __restrict__ fbt, const float* __restrict__ ow,
    const float* __restrict__ ob,
    float* __restrict__ g, float* __restrict__ fphgp, float* __restrict__ Srow,
    float* __restrict__ consts, float* __restrict__ eperm, float* __restrict__ cbperm,
    unsigned short* __restrict__ aextT, unsigned short* __restrict__ fpb)
{
    const int tx = threadIdx.x;
    if (blockIdx.x == 63) {
        // ---- prep ----
        if (tx < DD) {
            float c = fb1[tx];
#pragma unroll
            for (int d = 0; d < DD; ++d) c = fmaf(hbt[d], fw1[d*DD + tx], c);
            consts[tx] = c;
            const int r = tx & 15, hh = tx >> 4;
            const int d = (r & 3) + 8 * (r >> 2) + 4 * hh;
            eperm[tx]  = fg[d] * ow[d];
            cbperm[tx] = hbt[d] + fb2[d];
        }
        if (tx == 0) {
            float E = 0.f, F = ob[0];
#pragma unroll
            for (int d = 0; d < DD; ++d) { E += fg[d] * ow[d]; F = fmaf(fbt[d], ow[d], F); }
            consts[32] = E; consts[33] = F;
        }
        for (int idx = tx; idx < 32 * 32; idx += 64) {
            const int d = idx >> 5, k = idx & 31;
            __hip_bfloat16 b = __float2bfloat16(fw2[k * DD + d]);
            aextT[idx] = __builtin_bit_cast(unsigned short, b);
        }
        return;
    }
    const int m = blockIdx.x * 16 + (tx >> 2);
    const int q = tx & 3;
    if (m >= M_ROWS) return;
    const int b = tx & 60;          // group base lane (block = 1 wave)
    const int kb = q << 3;          // owned dim range [kb, kb+8)

    const f32x8 xo = *reinterpret_cast<const f32x8*>(feat + m * DD + kb);
    f32x8 X0, X1, X2, X3;
#pragma unroll
    for (int e = 0; e < 8; ++e) {
        X0[e] = __shfl(xo[e], b);     X1[e] = __shfl(xo[e], b + 1);
        X2[e] = __shfl(xo[e], b + 2); X3[e] = __shfl(xo[e], b + 3);
    }
    f32x8 h = *reinterpret_cast<const f32x8*>(ab1 + kb);
#pragma unroll
    for (int d = 0; d < DD; ++d) {
        const float xv = d < 8 ? X0[d] : d < 16 ? X1[d-8] : d < 24 ? X2[d-16] : X3[d-24];
        const f32x8 w = *reinterpret_cast<const f32x8*>(aw1 + d * DD + kb);
        h = h + xv * w;
    }
#pragma unroll
    for (int e = 0; e < 8; ++e) h[e] = fmaxf(h[e], 0.f);
    f32x8 H0, H1, H2, H3;
#pragma unroll
    for (int e = 0; e < 8; ++e) {
        H0[e] = __shfl(h[e], b);     H1[e] = __shfl(h[e], b + 1);
        H2[e] = __shfl(h[e], b + 2); H3[e] = __shfl(h[e], b + 3);
    }
    f32x8 y = xo + *reinterpret_cast<const f32x8*>(ab2 + kb);
#pragma unroll
    for (int k = 0; k < DD; ++k) {
        const float hv = k < 8 ? H0[k] : k < 16 ? H1[k-8] : k < 24 ? H2[k-16] : H3[k-24];
        const f32x8 w = *reinterpret_cast<const f32x8*>(aw2 + k * DD + kb);
        y = y + hv * w;
    }
    float sm = 0.f;
#pragma unroll
    for (int e = 0; e < 8; ++e) sm += y[e];
    const float mean = grp4_sum(sm) * (1.0f / DD);
    float vr = 0.f;
#pragma unroll
    for (int e = 0; e < 8; ++e) { const float tv = y[e] - mean; vr = fmaf(tv, tv, vr); }
    const float s = rsqrtf(grp4_sum(vr) * (1.0f / DD) + EPS);
    const f32x8 agv  = *reinterpret_cast<const f32x8*>(ag + kb);
    const f32x8 abtv = *reinterpret_cast<const f32x8*>(abt + kb);
    f32x8 f;
#pragma unroll
    for (int e = 0; e < 8; ++e) f[e] = (y[e] - mean) * s * agv[e] + abtv[e];
    float fs = 0.f;
#pragma unroll
    for (int e = 0; e < 8; ++e) fs += f[e];
    const float fm = grp4_sum(fs) * (1.0f / DD);
    const f32x8 fp = f - fm;
    float Sl = 0.f;
#pragma unroll
    for (int e = 0; e < 8; ++e) Sl = fmaf(fp[e], fp[e], Sl);
    const float S = grp4_sum(Sl);
    if (q == 0) Srow[m] = S;
    const f32x8 hgv = *reinterpret_cast<const f32x8*>(hg + kb);
    const f32x8 fph = fp * hgv;
    // C-layout permuted scatter of fphg
#pragma unroll
    for (int e = 0; e < 8; ++e)
        fphgp[m * DD + cperm(kb + e)] = fph[e];
    *reinterpret_cast<bf16x8*>(fpb + m * DD + kb) = cvt8(fp);
    // g row = fph_full @ fw1, lane's 8 outputs (natural order)
    f32x8 P0, P1, P2, P3;
#pragma unroll
    for (int e = 0; e < 8; ++e) {
        P0[e] = __shfl(fph[e], b);     P1[e] = __shfl(fph[e], b + 1);
        P2[e] = __shfl(fph[e], b + 2); P3[e] = __shfl(fph[e], b + 3);
    }
    f32x8 gr = {0.f,0.f,0.f,0.f,0.f,0.f,0.f,0.f};
#pragma unroll
    for (int d = 0; d < DD; ++d) {
        const float pv = d < 8 ? P0[d] : d < 16 ? P1[d-8] : d < 24 ? P2[d-16] : P3[d-24];
        const f32x8 w = *reinterpret_cast<const f32x8*>(fw1 + d * DD + kb);
        gr = gr + pv * w;
    }
    *reinterpret_cast<f32x8*>(g + m * DD + kb) = gr;
}

// ---------- pair head: symmetric, triangular flat grid (544 live blocks) ----------
// block = 16 i x 64 j; wave = 4 i x 64 j (8 tiles). Q in-wave via MFMA.
// C layout: col=l5=pair, row d=(r&3)+8*(r>>2)+4*h2
__global__ __launch_bounds__(256, 3) void pair_head_kernel(
    const float* __restrict__ g,      const float* __restrict__ fphgp,
    const float* __restrict__ Srow,   const float* __restrict__ ddg,
    const float* __restrict__ consts, const float* __restrict__ eperm,
    const float* __restrict__ cbperm, const unsigned short* __restrict__ aextT,
    const unsigned short* __restrict__ fpb,
    float* __restrict__ out)
{
    __shared__ float lds[64 * LROW];   // 17408 B
    __shared__ float lds2[64 * 17];    // 4352 B  res[j_local][i_local], stride 17

    const int tx   = threadIdx.x;
    const int wid  = tx >> 6;
    const int lane = tx & 63;
    const int l5   = lane & 31;
    const int h2   = lane >> 5;

    // triangular decode: block b -> (jg, iy); cum(jg) = 2jg^2+2jg; live rows 4jg+4
    const int bid = blockIdx.x;
    int jg = (int)((-1.0f + sqrtf(1.0f + 2.0f * (float)bid)) * 0.5f);
    while (2 * (jg + 1) * (jg + 1) + 2 * (jg + 1) <= bid) ++jg;
    while (2 * jg * jg + 2 * jg > bid) --jg;
    const int iy  = bid - (2 * jg * jg + 2 * jg);
    const int ib0 = iy * 16;                      // block's first i
    const int ib  = ib0 + wid * 4;                // wave's first i

    // ---- stage j-panel: 64 rows x (g 32f | fphgp 32f), one f32x16 per thread ----
    {
        const int r    = tx >> 2;          // row 0..63
        const int part = tx & 3;
        const int srcr = min(jg * 64 + r, M_ROWS - 1);
        const float* src = ((part >> 1) ? fphgp : g) + srcr * DD + (part & 1) * 16;
        float* dst = lds + r * LROW + (part >> 1) * 32 + (part & 1) * 16;
        *reinterpret_cast<f32x16*>(dst) = *reinterpret_cast<const f32x16*>(src);
    }

    // ---- Q via MFMA (overlaps the LDS stage; no LDS dependency) ----
    const int j0  = jg * 64 + l5;
    const int j1  = jg * 64 + 32 + l5;
    const int jc0 = j0 < M_ROWS ? j0 : M_ROWS - 1;
    const int jc1 = j1 < M_ROWS ? j1 : M_ROWS - 1;

    const int ia = min(ib + l5, M_ROWS - 1);   // A rows (only l5<4 read from C)
    const bf16x8 aq0 = *reinterpret_cast<const bf16x8*>(fpb + ia * DD + h2 * 8);
    const bf16x8 aq1 = *reinterpret_cast<const bf16x8*>(fpb + ia * DD + 16 + h2 * 8);

    float qv[8];
#pragma unroll
    for (int t = 0; t < 2; ++t) {
        const int jc = t ? jc1 : jc0;
        const bf16x8 bq0 = *reinterpret_cast<const bf16x8*>(fpb + jc * DD + h2 * 8);
        const bf16x8 bq1 = *reinterpret_cast<const bf16x8*>(fpb + jc * DD + 16 + h2 * 8);
        f32x16 qa;
#pragma unroll
        for (int r = 0; r < 16; ++r) qa[r] = 0.f;
        qa = __builtin_amdgcn_mfma_f32_32x32x16_bf16(aq0, bq0, qa, 0, 0, 0);
        qa = __builtin_amdgcn_mfma_f32_32x32x16_bf16(aq1, bq1, qa, 0, 0, 0);
#pragma unroll
        for (int ii = 0; ii < 4; ++ii) {
            const float other = __shfl_xor(qa[ii], 32);
            qv[2 * ii + t] = h2 ? other : qa[ii];
        }
    }

    const bf16x8 af0 = *reinterpret_cast<const bf16x8*>(aextT + l5 * 32 + h2 * 8);
    const bf16x8 af1 = *reinterpret_cast<const bf16x8*>(aextT + l5 * 32 + 16 + h2 * 8);

    const f32x8  ckA = *reinterpret_cast<const f32x8*>(consts + h2 * 8);
    const f32x8  ckB = *reinterpret_cast<const f32x8*>(consts + 16 + h2 * 8);
    const f32x16 cbp = *reinterpret_cast<const f32x16*>(cbperm + h2 * 16);
    const f32x16 ep  = *reinterpret_cast<const f32x16*>(eperm  + h2 * 16);
    const float E = consts[32];
    const float Fc = consts[33];

    const float Sj0 = Srow[jc0], Sj1 = Srow[jc1];
    const float dj0 = ddg[jc0],  dj1 = ddg[jc1];

    __syncthreads();

#pragma unroll
    for (int ii = 0; ii < 4; ++ii) {
        const int i  = ib + ii;
        const int ic = min(i, M_ROWS - 1);
        // i-side: wave-uniform addresses -> scalar loads
        const f32x8  gikA   = *reinterpret_cast<const f32x8*>(g + ic * DD + h2 * 8);
        const f32x8  gikB   = *reinterpret_cast<const f32x8*>(g + ic * DD + 16 + h2 * 8);
        const f32x16 fiperm = *reinterpret_cast<const f32x16*>(fphgp + ic * DD + h2 * 16);
        const float Si = Srow[ic];
        const float Fd = Fc + ddg[ic];

#pragma unroll
        for (int t = 0; t < 2; ++t) {
            const float* base = lds + (t * 32 + l5) * LROW;
            const f32x8  gjA = *reinterpret_cast<const f32x8*>(base + h2 * 8);
            const f32x8  gjB = *reinterpret_cast<const f32x8*>(base + 16 + h2 * 8);
            const f32x16 fjp = *reinterpret_cast<const f32x16*>(base + 32 + h2 * 16);
            const float Sj = t ? Sj1 : Sj0;
            const float dj = t ? dj1 : dj0;
            const float qd = qv[2 * ii + t];

            const float s = rsqrtf(fmaf(Si + Sj + 2.f * qd, 1.0f / DD, EPS));

            f32x8 tA = (gikA + gjA) * s + ckA;
            f32x8 tB = (gikB + gjB) * s + ckB;
#pragma unroll
            for (int e = 0; e < 8; ++e) { tA[e] = fmaxf(tA[e], 0.f); tB[e] = fmaxf(tB[e], 0.f); }
            const bf16x8 B0 = cvt8(tA);
            const bf16x8 B1 = cvt8(tB);

            f32x16 acc = cbp;
            acc = __builtin_amdgcn_mfma_f32_32x32x16_bf16(af0, B0, acc, 0, 0, 0);
            acc = __builtin_amdgcn_mfma_f32_32x32x16_bf16(af1, B1, acc, 0, 0, 0);

            float sy = 0.f, syy = 0.f, sye = 0.f;
#pragma unroll
            for (int r = 0; r < 16; ++r) {
                const float yv = fmaf(s, fiperm[r] + fjp[r], acc[r]);
                sy += yv; syy = fmaf(yv, yv, syy); sye = fmaf(yv, ep[r], sye);
            }
            sy  += __shfl_xor(sy, 32);
            syy += __shfl_xor(syy, 32);
            sye += __shfl_xor(sye, 32);
            const float m2   = sy * (1.0f / DD);
            const float var2 = fmaf(-m2, m2, syy * (1.0f / DD));
            const float s2   = rsqrtf(var2 + EPS);
            const float res  = fmaf(s2, fmaf(-m2, E, sye), Fd) + dj;
            const int j = jg * 64 + t * 32 + l5;
            if (h2 == 0) {
                lds2[(t * 32 + l5) * 17 + (wid * 4 + ii)] = res;
                if (j < M_ROWS && i < M_ROWS && i <= j) out[i * M_ROWS + j] = res;
            }
        }
    }

    __syncthreads();

    // ---- mirror: out[j][i] = res(i,j) for j > i, coalesced 16-lane segments ----
#pragma unroll
    for (int p = 0; p < 4; ++p) {
        const int jl = (tx >> 4) + p * 16;
        const int il = tx & 15;
        const int jgl = jg * 64 + jl;
        const int igl = ib0 + il;
        if (jgl > igl && jgl < M_ROWS && igl < M_ROWS)
            out[jgl * M_ROWS + igl] = lds2[jl * 17 + il];
    }
}

extern "C" void kernel_launch(void* const* d_in, const int* in_sizes, int n_in,
                              void* d_out, int out_size, void* d_ws, size_t ws_size,
                              hipStream_t stream) {
    const float* feat = (const float*)d_in[0];
    const float* ddg  = (const float*)d_in[1];
    const float* aw1  = (const float*)d_in[2];
    const float* ab1  = (const float*)d_in[3];
    const float* aw2  = (const float*)d_in[4];
    const float* ab2  = (const float*)d_in[5];
    const float* ag   = (const float*)d_in[6];
    const float* abt  = (const float*)d_in[7];
    const float* hg   = (const float*)d_in[8];
    const float* hbt  = (const float*)d_in[9];
    const float* fw1  = (const float*)d_in[10];
    const float* fb1  = (const float*)d_in[11];
    const float* fw2  = (const float*)d_in[12];
    const float* fb2  = (const float*)d_in[13];
    const float* fg   = (const float*)d_in[14];
    const float* fbt  = (const float*)d_in[15];
    const float* ow   = (const float*)d_in[16];
    const float* ob   = (const float*)d_in[17];
    float* out = (float*)d_out;

    float* ws      = (float*)d_ws;
    float* g       = ws;             // 32000
    float* fphgp   = ws + 32000;     // 32000
    float* Srow    = ws + 64000;     // 1024
    float* consts  = ws + 65024;     // 64
    float* eperm   = ws + 65088;     // 32
    float* cbperm  = ws + 65120;     // 32
    unsigned short* aextT = (unsigned short*)(ws + 65152);  // 1024 ushorts
    unsigned short* fpb   = (unsigned short*)(ws + 65664);  // 32000 ushorts

    front_kernel<<<dim3(64), dim3(64), 0, stream>>>(
        feat, aw1, ab1, aw2, ab2, ag, abt, hg,
        fw1, fb1, hbt, fw2, fb2, fg, fbt, ow, ob,
        g, fphgp, Srow, consts, eperm, cbperm, aextT, fpb);
    pair_head_kernel<<<dim3(544), dim3(256), 0, stream>>>(
        g, fphgp, Srow, ddg, consts, eperm, cbperm, aextT, fpb, out);
}